// Round 3
// baseline (325.717 us; speedup 1.0000x reference)
//
#include <hip/hip_runtime.h>
#include <hip/hip_fp16.h>
#include <stdint.h>

typedef _Float16 f16;
typedef f16   f16x8 __attribute__((ext_vector_type(8)));
typedef float f32x4 __attribute__((ext_vector_type(4)));

#define NTOK 262144
#define DDIM 256
#define KCB  1024
#define GG   4
#define CC   64
#define FR   4            // 16-row fragments per wave (64 rows/wave)
#define NBLKX (NTOK / (FR * 16 * 4))   // 1024
#define NPART (NBLKX * GG)             // 4096 per-block loss partials

static __device__ __forceinline__ uint32_t umin32(uint32_t a, uint32_t b) { return a < b ? a : b; }

// ---------------- prep: fp32 codebook -> fp16 copy + (0.5 + ||e||^2) table
__global__ __launch_bounds__(64) void vq_prep(const float* __restrict__ cb,
                                              f16* __restrict__ cb16,
                                              float* __restrict__ esq05) {
    int gk = blockIdx.x;          // 0 .. G*K-1
    int c  = threadIdx.x;         // 0 .. 63
    float v = cb[(size_t)gk * CC + c];
    cb16[(size_t)gk * CC + c] = (f16)v;
    float s = v * v;
    #pragma unroll
    for (int off = 32; off; off >>= 1) s += __shfl_down(s, off, 64);
    if (c == 0) esq05[gk] = 0.5f + s;
}

// ---------------- main: fused dots (MFMA fp16) + packed-key argmin + gather + loss partial
__global__ __launch_bounds__(256, 4) void vq_main(const float* __restrict__ z,
                                                  const float* __restrict__ cb32,
                                                  const f16* __restrict__ cb16,
                                                  const float* __restrict__ esq05,
                                                  float* __restrict__ out,
                                                  float* __restrict__ part) {
    const int lane = threadIdx.x & 63;
    const int w    = threadIdx.x >> 6;                 // wave id (0..3)
    const int g    = blockIdx.y;                       // group
    const int r0   = blockIdx.x * (FR * 16 * 4) + w * (FR * 16);  // wave's base row
    const int q    = lane >> 4;                        // quarter (k-chunk selector)
    const int t    = lane & 15;                        // within-16 id

    // ---- load A fragments (FR x 16 rows, K=64 split in two 32-halves), fp32 -> fp16, scaled by -2
    // A layout for mfma_f32_16x16x32_f16: lane holds row (lane&15), k = (lane>>4)*8 + j
    f16x8 a[FR][2];
    float zsq[FR];
    #pragma unroll
    for (int f = 0; f < FR; ++f) {
        int row = r0 + f * 16 + t;
        const float* zp = z + (size_t)row * DDIM + g * CC + q * 8;
        float4 v0 = *(const float4*)(zp);
        float4 v1 = *(const float4*)(zp + 4);
        float4 v2 = *(const float4*)(zp + 32);
        float4 v3 = *(const float4*)(zp + 36);
        f16x8 a0 = { (f16)(-2.f*v0.x),(f16)(-2.f*v0.y),(f16)(-2.f*v0.z),(f16)(-2.f*v0.w),
                     (f16)(-2.f*v1.x),(f16)(-2.f*v1.y),(f16)(-2.f*v1.z),(f16)(-2.f*v1.w) };
        f16x8 a1 = { (f16)(-2.f*v2.x),(f16)(-2.f*v2.y),(f16)(-2.f*v2.z),(f16)(-2.f*v2.w),
                     (f16)(-2.f*v3.x),(f16)(-2.f*v3.y),(f16)(-2.f*v3.z),(f16)(-2.f*v3.w) };
        a[f][0] = a0; a[f][1] = a1;
        float s = v0.x*v0.x + v0.y*v0.y + v0.z*v0.z + v0.w*v0.w
                + v1.x*v1.x + v1.y*v1.y + v1.z*v1.z + v1.w*v1.w
                + v2.x*v2.x + v2.y*v2.y + v2.z*v2.z + v2.w*v2.w
                + v3.x*v3.x + v3.y*v3.y + v3.z*v3.z + v3.w*v3.w;
        s += __shfl_xor(s, 16, 64);
        s += __shfl_xor(s, 32, 64);
        zsq[f] = s;   // lane l holds full ||z_g||^2 for row (l&15)
    }

    uint32_t run[FR][4];
    #pragma unroll
    for (int f = 0; f < FR; ++f)
        #pragma unroll
        for (int i = 0; i < 4; ++i) run[f][i] = 0xFFFFFFFFu;

    const f16*   cbg = cb16  + (size_t)g * KCB * CC;
    const float* eg  = esq05 + (size_t)g * KCB;

    // ---- prologue: load first 32-code tile (two 16-code subtiles A/B)
    f16x8 cb0A, cb1A, cb0B, cb1B; float ceA, ceB;
    {
        const f16x8* bp = (const f16x8*)(cbg + (size_t)t * CC + q * 8);
        cb0A = bp[0];  cb1A = bp[4];          // codes t      (k 0..31 / 32..63)
        cb0B = bp[128]; cb1B = bp[132];       // codes 16+t   (+16*64 f16 = +128 f16x8... byte +2048)
        ceA = eg[t]; ceB = eg[16 + t];
    }

    // ---- K-code loop: 32 codes per iteration, prefetched one full iteration (~32 codes) ahead
    for (int n0 = 0; n0 < KCB; n0 += 32) {
        int nn = (n0 + 32) & (KCB - 1);                 // wrap -> harmless redundant load
        const f16x8* nbp = (const f16x8*)(cbg + (size_t)(nn + t) * CC + q * 8);
        f16x8 nb0A = nbp[0];
        f16x8 nb1A = nbp[4];
        f16x8 nb0B = nbp[128];
        f16x8 nb1B = nbp[132];
        float neA  = eg[nn + t];
        float neB  = eg[nn + 16 + t];

        uint32_t codeA = (uint32_t)(n0 + t);
        f32x4 cqA = { ceA, ceA, ceA, ceA };             // d = (0.5+esq) + (-2z)·e
        f32x4 cqB = { ceB, ceB, ceB, ceB };
        #pragma unroll
        for (int f = 0; f < FR; ++f) {
            f32x4 accA = __builtin_amdgcn_mfma_f32_16x16x32_f16(a[f][0], cb0A, cqA, 0, 0, 0);
            accA = __builtin_amdgcn_mfma_f32_16x16x32_f16(a[f][1], cb1A, accA, 0, 0, 0);
            f32x4 accB = __builtin_amdgcn_mfma_f32_16x16x32_f16(a[f][0], cb0B, cqB, 0, 0, 0);
            accB = __builtin_amdgcn_mfma_f32_16x16x32_f16(a[f][1], cb1B, accB, 0, 0, 0);
            // C/D layout: col = lane&15 (code), row = (lane>>4)*4 + i
            #pragma unroll
            for (int i = 0; i < 4; ++i) {
                uint32_t kA = (__float_as_uint(accA[i]) & 0xFFFFFC00u) | codeA;        // v_and_or_b32
                uint32_t kB = (__float_as_uint(accB[i]) & 0xFFFFFC00u) | (codeA + 16); // v_and_or_b32
                run[f][i] = umin32(run[f][i], umin32(kA, kB));                         // -> v_min3_u32
            }
        }
        cb0A = nb0A; cb1A = nb1A; cb0B = nb0B; cb1B = nb1B; ceA = neA; ceB = neB;
    }

    // ---- epilogue: cross-lane argmin, gather fp32 code rows, loss partials
    float lsum = 0.0f;
    #pragma unroll
    for (int f = 0; f < FR; ++f) {
        #pragma unroll
        for (int i = 0; i < 4; ++i) {
            uint32_t k = run[f][i];
            k = umin32(k, __shfl_xor(k, 1, 64));
            k = umin32(k, __shfl_xor(k, 2, 64));
            k = umin32(k, __shfl_xor(k, 4, 64));
            k = umin32(k, __shfl_xor(k, 8, 64));   // 16 lanes of each quarter now agree
            int   kw     = (int)(k & 1023u);
            float minval = __uint_as_float(k & 0xFFFFFC00u) - 0.5f;  // esq - 2*dot (truncated)
            int rloc = q * 4 + i;                  // row within this 16-row fragment
            int grow = r0 + f * 16 + rloc;         // global row
            // copy exact fp32 codebook row (256B) with the 16 lanes of this quarter
            const float4* src = (const float4*)(cb32 + ((size_t)(g * KCB + kw)) * CC) + t;
            float4*       dst = (float4*)(out + (size_t)grow * DDIM + g * CC) + t;
            *dst = *src;
            float zs = __shfl(zsq[f], rloc, 64);   // ||z_g||^2 of row rloc (held by lane rloc)
            if (t == 0) lsum += zs + minval;       // Σ_c (zq - zg)^2 for this (row, group)
        }
    }
    #pragma unroll
    for (int off = 32; off; off >>= 1) lsum += __shfl_down(lsum, off, 64);

    // ---- block-level loss partial: LDS reduce across the 4 waves, one plain store per block
    __shared__ float ls[4];
    if (lane == 0) ls[w] = lsum;
    __syncthreads();
    if (threadIdx.x == 0) {
        part[blockIdx.y * NBLKX + blockIdx.x] = ls[0] + ls[1] + ls[2] + ls[3];
    }
}

// ---------------- finalize: reduce 4096 per-block partials into the loss scalar
__global__ __launch_bounds__(256) void vq_final(const float* __restrict__ part,
                                                float* __restrict__ out_loss) {
    __shared__ float ls[4];
    float s = 0.0f;
    for (int i = threadIdx.x; i < NPART; i += 256) s += part[i];
    #pragma unroll
    for (int off = 32; off; off >>= 1) s += __shfl_down(s, off, 64);
    int lane = threadIdx.x & 63, w = threadIdx.x >> 6;
    if (lane == 0) ls[w] = s;
    __syncthreads();
    if (threadIdx.x == 0) {
        // loss = mean_g(BETA*commit + embed) = 1.5 * total_sq_err / (N*D)
        *out_loss = 1.5f * (ls[0] + ls[1] + ls[2] + ls[3]) * (1.0f / ((float)NTOK * (float)DDIM));
    }
}

extern "C" void kernel_launch(void* const* d_in, const int* in_sizes, int n_in,
                              void* d_out, int out_size, void* d_ws, size_t ws_size,
                              hipStream_t stream) {
    const float* z  = (const float*)d_in[0];
    const float* cb = (const float*)d_in[1];
    float* out = (float*)d_out;

    char* ws = (char*)d_ws;
    f16*   cb16  = (f16*)ws;                                             // 512 KB
    float* esq05 = (float*)(ws + (size_t)GG * KCB * CC * sizeof(f16));   // 16 KB
    float* part  = (float*)(ws + (size_t)GG * KCB * CC * sizeof(f16)
                               + (size_t)GG * KCB * sizeof(float));      // 16 KB

    vq_prep<<<GG * KCB, 64, 0, stream>>>(cb, cb16, esq05);

    dim3 grid(NBLKX, GG);   // 1024 x 4
    vq_main<<<grid, 256, 0, stream>>>(z, cb, cb16, esq05, out, part);

    vq_final<<<1, 256, 0, stream>>>(part, out + (size_t)NTOK * DDIM);
}

// Round 4
// 224.436 us; speedup vs baseline: 1.4513x; 1.4513x over previous
//
#include <hip/hip_runtime.h>
#include <hip/hip_fp16.h>
#include <stdint.h>

typedef _Float16 f16;
typedef f16   f16x8 __attribute__((ext_vector_type(8)));
typedef float f32x4 __attribute__((ext_vector_type(4)));

#define NTOK 262144
#define DDIM 256
#define KCB  1024
#define GG   4
#define CC   64
#define FR   8                          // 16-row fragments per wave (128 rows/wave)
#define ROWS_PER_BLK (FR * 16 * 4)      // 512
#define NBLKX (NTOK / ROWS_PER_BLK)     // 512
#define NPART (NBLKX * GG)              // 2048 per-block loss partials
#define TILE_K 64                       // codes per staged LDS tile
#define NTILE  (KCB / TILE_K)           // 16
#define TILE_B (TILE_K * CC * 2)        // 8192 bytes of fp16 codes per tile

static __device__ __forceinline__ uint32_t umin32(uint32_t a, uint32_t b) { return a < b ? a : b; }

typedef __attribute__((address_space(1))) const void gv_t;
typedef __attribute__((address_space(3))) void lv_t;
static __device__ __forceinline__ void gl_lds16(const void* g, void* l) {
    __builtin_amdgcn_global_load_lds((gv_t*)g, (lv_t*)l, 16, 0, 0);
}
static __device__ __forceinline__ void gl_lds4(const void* g, void* l) {
    __builtin_amdgcn_global_load_lds((gv_t*)g, (lv_t*)l, 4, 0, 0);
}

// ---------------- prep: fp32 codebook -> fp16 copy + (0.5 + ||e||^2) table
__global__ __launch_bounds__(64) void vq_prep(const float* __restrict__ cb,
                                              f16* __restrict__ cb16,
                                              float* __restrict__ esq05) {
    int gk = blockIdx.x;          // 0 .. G*K-1
    int c  = threadIdx.x;         // 0 .. 63
    float v = cb[(size_t)gk * CC + c];
    cb16[(size_t)gk * CC + c] = (f16)v;
    float s = v * v;
    #pragma unroll
    for (int off = 32; off; off >>= 1) s += __shfl_down(s, off, 64);
    if (c == 0) esq05[gk] = 0.5f + s;
}

// ---------------- main: LDS-staged codebook + MFMA + packed-key argmin + gather + loss partial
__global__ __launch_bounds__(256, 3) void vq_main(const float* __restrict__ z,
                                                  const float* __restrict__ cb32,
                                                  const f16* __restrict__ cb16,
                                                  const float* __restrict__ esq05,
                                                  float* __restrict__ out,
                                                  float* __restrict__ part) {
    const int lane = threadIdx.x & 63;
    const int w    = threadIdx.x >> 6;                 // wave id (0..3)
    const int g    = blockIdx.y;                       // group
    const int r0   = blockIdx.x * ROWS_PER_BLK + w * (FR * 16);  // wave's base row
    const int q    = lane >> 4;                        // quarter (k-chunk selector)
    const int t    = lane & 15;                        // within-16 id

    // double-buffered codebook tile (swizzled image) + e tile
    __shared__ __align__(16) char sb[2][TILE_B + 256];
    __shared__ float ls[4];

    const f16*   cbg = cb16  + (size_t)g * KCB * CC;
    const float* eg  = esq05 + (size_t)g * KCB;

    // stage tile `tile` into buffer `bufsel`.
    // LDS image: LDS[code*128 + b'] = logical(code, b' ^ ((code&7)<<4))  -> pre-swizzled SOURCE,
    // linear global_load_lds dest (wave-uniform base + lane*16), swizzled ds_read (G21).
    auto stage = [&](int tile, int bufsel) {
        const char* gtile = (const char*)cbg + (size_t)tile * TILE_B;
        #pragma unroll
        for (int c2 = 0; c2 < 2; ++c2) {
            uint32_t x  = (uint32_t)(w * 2048 + c2 * 1024 + lane * 16);   // tile-local dest byte
            uint32_t gx = x ^ (((x >> 7) & 7u) << 4);                     // inverse-swizzled source
            gl_lds16(gtile + gx, &sb[bufsel][w * 2048 + c2 * 1024]);      // per-lane src, uniform dest base
        }
        if (w == 0) gl_lds4(eg + tile * TILE_K + lane, &sb[bufsel][TILE_B]);
    };

    // ---- issue stage of tile 0 first so it overlaps the z prologue
    stage(0, 0);

    // ---- load A fragments (FR x 16 rows, K=64 in two 32-halves), fp32 -> fp16, scaled by -2
    // A layout for mfma_f32_16x16x32_f16: lane holds row (lane&15), k = (lane>>4)*8 + j
    f16x8 a[FR][2];
    float zsq[FR];
    #pragma unroll
    for (int f = 0; f < FR; ++f) {
        int row = r0 + f * 16 + t;
        const float* zp = z + (size_t)row * DDIM + g * CC + q * 8;
        float4 v0 = *(const float4*)(zp);
        float4 v1 = *(const float4*)(zp + 4);
        float4 v2 = *(const float4*)(zp + 32);
        float4 v3 = *(const float4*)(zp + 36);
        f16x8 a0 = { (f16)(-2.f*v0.x),(f16)(-2.f*v0.y),(f16)(-2.f*v0.z),(f16)(-2.f*v0.w),
                     (f16)(-2.f*v1.x),(f16)(-2.f*v1.y),(f16)(-2.f*v1.z),(f16)(-2.f*v1.w) };
        f16x8 a1 = { (f16)(-2.f*v2.x),(f16)(-2.f*v2.y),(f16)(-2.f*v2.z),(f16)(-2.f*v2.w),
                     (f16)(-2.f*v3.x),(f16)(-2.f*v3.y),(f16)(-2.f*v3.z),(f16)(-2.f*v3.w) };
        a[f][0] = a0; a[f][1] = a1;
        float s = v0.x*v0.x + v0.y*v0.y + v0.z*v0.z + v0.w*v0.w
                + v1.x*v1.x + v1.y*v1.y + v1.z*v1.z + v1.w*v1.w
                + v2.x*v2.x + v2.y*v2.y + v2.z*v2.z + v2.w*v2.w
                + v3.x*v3.x + v3.y*v3.y + v3.z*v3.z + v3.w*v3.w;
        s += __shfl_xor(s, 16, 64);
        s += __shfl_xor(s, 32, 64);
        zsq[f] = s;   // lane l holds full ||z_g||^2 for row (l&15)
    }

    uint32_t run[FR][4];
    #pragma unroll
    for (int f = 0; f < FR; ++f)
        #pragma unroll
        for (int i = 0; i < 4; ++i) run[f][i] = 0xFFFFFFFFu;

    // per-lane constant part of the swizzled ds_read address (b0); b1 = ^64
    const uint32_t binner = (uint32_t)t * 128 + (((uint32_t)(q * 16)) ^ (((uint32_t)(t & 7)) << 4));

    // ---- tile loop: one barrier per tile; stage(t+1) in flight across compute(t)
    for (int tt = 0; tt < NTILE; ++tt) {
        __syncthreads();                               // drains vmcnt (stage tt done) + lgkm; all waves past reads of other buf
        if (tt + 1 < NTILE) stage(tt + 1, (tt + 1) & 1);
        const char*  bb = sb[tt & 1];
        const float* eb = (const float*)(sb[tt & 1] + TILE_B);
        #pragma unroll
        for (int sub = 0; sub < 4; ++sub) {
            f16x8 b0 = *(const f16x8*)(bb + sub * 2048 + binner);
            f16x8 b1 = *(const f16x8*)(bb + sub * 2048 + (binner ^ 64));
            float e  = eb[sub * 16 + t];
            f32x4 ce = { e, e, e, e };                 // d = (0.5+esq) + (-2z)·e
            uint32_t code = (uint32_t)(tt * TILE_K + sub * 16 + t);
            #pragma unroll
            for (int f = 0; f < FR; ++f) {
                f32x4 acc = __builtin_amdgcn_mfma_f32_16x16x32_f16(a[f][0], b0, ce, 0, 0, 0);
                acc = __builtin_amdgcn_mfma_f32_16x16x32_f16(a[f][1], b1, acc, 0, 0, 0);
                // C/D layout: col = lane&15 (code), row = (lane>>4)*4 + i
                #pragma unroll
                for (int i = 0; i < 4; ++i) {
                    uint32_t k = (__float_as_uint(acc[i]) & 0xFFFFFC00u) | code; // v_and_or_b32
                    run[f][i] = umin32(run[f][i], k);                           // v_min_u32
                }
            }
        }
    }

    // ---- epilogue: cross-lane argmin, gather fp32 code rows, loss partials
    float lsum = 0.0f;
    #pragma unroll
    for (int f = 0; f < FR; ++f) {
        #pragma unroll
        for (int i = 0; i < 4; ++i) {
            uint32_t k = run[f][i];
            k = umin32(k, __shfl_xor(k, 1, 64));
            k = umin32(k, __shfl_xor(k, 2, 64));
            k = umin32(k, __shfl_xor(k, 4, 64));
            k = umin32(k, __shfl_xor(k, 8, 64));   // 16 lanes of each quarter now agree
            int   kw     = (int)(k & 1023u);
            float minval = __uint_as_float(k & 0xFFFFFC00u) - 0.5f;  // esq - 2*dot (truncated)
            int rloc = q * 4 + i;                  // row within this 16-row fragment
            int grow = r0 + f * 16 + rloc;         // global row
            // copy exact fp32 codebook row (256B) with the 16 lanes of this quarter
            const float4* src = (const float4*)(cb32 + ((size_t)(g * KCB + kw)) * CC) + t;
            float4*       dst = (float4*)(out + (size_t)grow * DDIM + g * CC) + t;
            *dst = *src;
            float zs = __shfl(zsq[f], rloc, 64);   // ||z_g||^2 of row rloc (held by lane rloc)
            if (t == 0) lsum += zs + minval;       // Σ_c (zq - zg)^2 for this (row, group)
        }
    }
    #pragma unroll
    for (int off = 32; off; off >>= 1) lsum += __shfl_down(lsum, off, 64);

    // ---- block-level loss partial: LDS reduce across the 4 waves, one plain store per block
    if (lane == 0) ls[w] = lsum;
    __syncthreads();
    if (threadIdx.x == 0) {
        part[blockIdx.y * NBLKX + blockIdx.x] = ls[0] + ls[1] + ls[2] + ls[3];
    }
}

// ---------------- finalize: reduce per-block partials into the loss scalar
__global__ __launch_bounds__(256) void vq_final(const float* __restrict__ part,
                                                float* __restrict__ out_loss) {
    __shared__ float ls[4];
    float s = 0.0f;
    for (int i = threadIdx.x; i < NPART; i += 256) s += part[i];
    #pragma unroll
    for (int off = 32; off; off >>= 1) s += __shfl_down(s, off, 64);
    int lane = threadIdx.x & 63, w = threadIdx.x >> 6;
    if (lane == 0) ls[w] = s;
    __syncthreads();
    if (threadIdx.x == 0) {
        // loss = mean_g(BETA*commit + embed) = 1.5 * total_sq_err / (N*D)
        *out_loss = 1.5f * (ls[0] + ls[1] + ls[2] + ls[3]) * (1.0f / ((float)NTOK * (float)DDIM));
    }
}

extern "C" void kernel_launch(void* const* d_in, const int* in_sizes, int n_in,
                              void* d_out, int out_size, void* d_ws, size_t ws_size,
                              hipStream_t stream) {
    const float* z  = (const float*)d_in[0];
    const float* cb = (const float*)d_in[1];
    float* out = (float*)d_out;

    char* ws = (char*)d_ws;
    f16*   cb16  = (f16*)ws;                                             // 512 KB
    float* esq05 = (float*)(ws + (size_t)GG * KCB * CC * sizeof(f16));   // 16 KB
    float* part  = (float*)(ws + (size_t)GG * KCB * CC * sizeof(f16)
                               + (size_t)GG * KCB * sizeof(float));      // 8 KB

    vq_prep<<<GG * KCB, 64, 0, stream>>>(cb, cb16, esq05);

    dim3 grid(NBLKX, GG);   // 512 x 4
    vq_main<<<grid, 256, 0, stream>>>(z, cb, cb16, esq05, out, part);

    vq_final<<<1, 256, 0, stream>>>(part, out + (size_t)NTOK * DDIM);
}